// Round 3
// baseline (204.505 us; speedup 1.0000x reference)
//
#include <hip/hip_runtime.h>
#include <math.h>

// Problem constants (B,T,D,H,L from the reference)
#define BB 4
#define TT 2048
#define DD 512
#define HH 8
#define NLAYER 2
#define EPS 1e-5f
#define SCALE 0.125f            // dh^-0.5, dh=64

#define NTILE 128               // partial tiles per batch (= blocks/batch in emitters)
#define RPW 4                   // rows per wave in emitters (16 rows per block)

// ---------------------------------------------------------------------------
// Initial masked LN-sum (only needed once, for the very first phase's keys).
// Grid: BB*NTILE blocks, 256 threads; 4 waves x RPW rows; per-block LDS
// reduce -> partial[b][tile][d].
// ---------------------------------------------------------------------------
__global__ __launch_bounds__(256) void ln_masked_sum_kernel(
    const float* __restrict__ x,      // (B,T,D)
    const int*   __restrict__ kpm,    // (B,T) flat; nonzero = masked out
    const float* __restrict__ gamma,  // (D)
    const float* __restrict__ beta,   // (D)
    float* __restrict__ partial)      // (B, NTILE, D)
{
  const int bk   = blockIdx.x;
  const int wave = threadIdx.x >> 6;
  const int lane = threadIdx.x & 63;
  const int b    = bk >> 7;
  const int tile = bk & (NTILE - 1);
  const int row0 = bk * 16 + wave * RPW;   // global row = b*TT + t

  __shared__ float lds[4][DD];

  float4 g0 = *reinterpret_cast<const float4*>(gamma + lane * 4);
  float4 g1 = *reinterpret_cast<const float4*>(gamma + 256 + lane * 4);
  float4 be0 = *reinterpret_cast<const float4*>(beta + lane * 4);
  float4 be1 = *reinterpret_cast<const float4*>(beta + 256 + lane * 4);
  float gv[8] = {g0.x, g0.y, g0.z, g0.w, g1.x, g1.y, g1.z, g1.w};
  float bv[8] = {be0.x, be0.y, be0.z, be0.w, be1.x, be1.y, be1.z, be1.w};

  float acc[8] = {0.f, 0.f, 0.f, 0.f, 0.f, 0.f, 0.f, 0.f};

  for (int r = 0; r < RPW; ++r) {
    const int row = row0 + r;
    const float* xr = x + (size_t)row * DD;
    float4 a0 = *reinterpret_cast<const float4*>(xr + lane * 4);
    float4 a1 = *reinterpret_cast<const float4*>(xr + 256 + lane * 4);
    float v[8] = {a0.x, a0.y, a0.z, a0.w, a1.x, a1.y, a1.z, a1.w};
    float s = 0.f, s2 = 0.f;
#pragma unroll
    for (int k = 0; k < 8; ++k) { s += v[k]; s2 += v[k] * v[k]; }
#pragma unroll
    for (int off = 32; off > 0; off >>= 1) {
      s  += __shfl_xor(s, off);
      s2 += __shfl_xor(s2, off);
    }
    const float mean = s * (1.f / (float)DD);
    const float var  = s2 * (1.f / (float)DD) - mean * mean;
    const float rstd = rsqrtf(var + EPS);
    if (kpm[row] == 0) {   // wave-uniform branch
#pragma unroll
      for (int k = 0; k < 8; ++k) acc[k] += (v[k] - mean) * rstd * gv[k] + bv[k];
    }
  }

#pragma unroll
  for (int k = 0; k < 4; ++k) {
    lds[wave][lane * 4 + k]       = acc[k];
    lds[wave][256 + lane * 4 + k] = acc[4 + k];
  }
  __syncthreads();

  const int tid = threadIdx.x;
  float s0 = lds[0][tid] + lds[1][tid] + lds[2][tid] + lds[3][tid];
  float s1 = lds[0][tid + 256] + lds[1][tid + 256] + lds[2][tid + 256] + lds[3][tid + 256];
  float* p = partial + ((size_t)b * NTILE + tile) * DD;
  p[tid]       = s0;
  p[tid + 256] = s1;
}

// ---------------------------------------------------------------------------
// prep: per (b,h) block: nsum (redundant per-block reduce of partials, L2),
// valid count -> fac/flag, ks (64 rows of Wk . nsum), m[b,h,:] = Wq^T ks *fac.
// Grid: BB*HH = 32 blocks, 256 threads.
// ---------------------------------------------------------------------------
__global__ __launch_bounds__(256) void prep_kernel(
    const float* __restrict__ partial,  // (B,NTILE,D)
    const int*   __restrict__ kpm,      // (B,T) flat
    const float* __restrict__ Wk,       // (D,D) layer slice, row o, col d
    const float* __restrict__ Wq,       // (D,D) layer slice
    float* __restrict__ m,              // (B,H,D)
    float* __restrict__ flag)           // (B)
{
  const int b    = blockIdx.x >> 3;
  const int h    = blockIdx.x & 7;
  const int tid  = threadIdx.x;
  const int wave = tid >> 6;
  const int lane = tid & 63;

  __shared__ float nsum[DD];
  __shared__ float ksl[64];
  __shared__ float csh[4];

  // 1. nsum[d] = sum over NTILE partial tiles (coalesced across tid per tile)
  for (int d = tid; d < DD; d += 256) {
    float s = 0.f;
    const float* p = partial + (size_t)b * NTILE * DD + d;
#pragma unroll 8
    for (int w = 0; w < NTILE; ++w) s += p[(size_t)w * DD];
    nsum[d] = s;
  }

  // 2. valid count
  int cnt = 0;
  for (int t = tid; t < TT; t += 256) cnt += (kpm[b * TT + t] == 0) ? 1 : 0;
#pragma unroll
  for (int off = 32; off > 0; off >>= 1) cnt += __shfl_xor(cnt, off);
  if (lane == 0) csh[wave] = (float)cnt;
  __syncthreads();

  const float vc = csh[0] + csh[1] + csh[2] + csh[3];
  if (h == 0 && tid == 0) flag[b] = (vc > 0.f) ? 1.f : 0.f;
  const float facv = SCALE / fmaxf(vc, 1.f);

  // 3. ks[j] = fac * Wk[h*64+j,:] . nsum  (wave w -> j in [w*16, w*16+16))
  float nl[8];
#pragma unroll
  for (int k = 0; k < 8; ++k) nl[k] = nsum[lane * 8 + k];
  for (int j = wave * 16; j < wave * 16 + 16; ++j) {
    const float* wr = Wk + (size_t)(h * 64 + j) * DD + lane * 8;
    float4 w0 = *reinterpret_cast<const float4*>(wr);
    float4 w1 = *reinterpret_cast<const float4*>(wr + 4);
    float s = w0.x * nl[0] + w0.y * nl[1] + w0.z * nl[2] + w0.w * nl[3] +
              w1.x * nl[4] + w1.y * nl[5] + w1.z * nl[6] + w1.w * nl[7];
#pragma unroll
    for (int off = 32; off > 0; off >>= 1) s += __shfl_xor(s, off);
    if (lane == 0) ksl[j] = s * facv;
  }
  __syncthreads();

  // 4. m[b,h,d] = sum_j Wq[h*64+j][d] * ks[j]  (coalesced across d)
  for (int d = tid; d < DD; d += 256) {
    float s = 0.f;
    const float* base = Wq + (size_t)(h * 64) * DD + d;
#pragma unroll 8
    for (int j = 0; j < 64; ++j) s += base[(size_t)j * DD] * ksl[j];
    m[((size_t)b * HH + h) * DD + d] = s;
  }
}

// ---------------------------------------------------------------------------
// update: per-row LN, rel[h] = n . m[b,h,:], gate MLP, out = x*(1+flag*sig(z)).
// ALSO emits the NEXT phase's masked LN-sum partials from the freshly written
// output rows (LN stats of y = v*sc derived from v's stats for free).
// Grid: BB*NTILE = 512 blocks, 256 threads, 4 waves x RPW rows.
// ---------------------------------------------------------------------------
__global__ __launch_bounds__(256) void update_kernel(
    const float* __restrict__ xin,     // (B,T,D)
    const float* __restrict__ gamma,   // (D)   this phase's LN (query side)
    const float* __restrict__ beta,    // (D)
    const float* __restrict__ m,       // (B,H,D)
    const float* __restrict__ flag,    // (B)
    const float* __restrict__ W1,      // (16,8)
    const float* __restrict__ b1,      // (16)
    const float* __restrict__ W2,      // (16)
    const float* __restrict__ b2,      // (1)
    const int*   __restrict__ kpm_next,// (B,T) flat — next phase's KEY mask
    const float* __restrict__ gnext,   // (D)   next phase's LN gamma
    const float* __restrict__ bnext,   // (D)
    float* __restrict__ xout,          // (B,T,D)
    float* __restrict__ partial,       // (B,NTILE,D)
    int emit)
{
  const int bk   = blockIdx.x;
  const int wave = threadIdx.x >> 6;
  const int lane = threadIdx.x & 63;
  const int b    = bk >> 7;
  const int tile = bk & (NTILE - 1);
  const int row0 = bk * 16 + wave * RPW;

  __shared__ float lds[4][DD];

  float4 g0 = *reinterpret_cast<const float4*>(gamma + lane * 4);
  float4 g1 = *reinterpret_cast<const float4*>(gamma + 256 + lane * 4);
  float4 be0 = *reinterpret_cast<const float4*>(beta + lane * 4);
  float4 be1 = *reinterpret_cast<const float4*>(beta + 256 + lane * 4);
  float gv[8] = {g0.x, g0.y, g0.z, g0.w, g1.x, g1.y, g1.z, g1.w};
  float bv[8] = {be0.x, be0.y, be0.z, be0.w, be1.x, be1.y, be1.z, be1.w};

  float4 gn0 = *reinterpret_cast<const float4*>(gnext + lane * 4);
  float4 gn1 = *reinterpret_cast<const float4*>(gnext + 256 + lane * 4);
  float4 bn0 = *reinterpret_cast<const float4*>(bnext + lane * 4);
  float4 bn1 = *reinterpret_cast<const float4*>(bnext + 256 + lane * 4);
  float gnv[8] = {gn0.x, gn0.y, gn0.z, gn0.w, gn1.x, gn1.y, gn1.z, gn1.w};
  float bnv[8] = {bn0.x, bn0.y, bn0.z, bn0.w, bn1.x, bn1.y, bn1.z, bn1.w};

  // hoist m fragments (same for all rows of this batch)
  const float* mb = m + (size_t)b * HH * DD;
  float4 mA[HH], mB[HH];
#pragma unroll
  for (int h = 0; h < HH; ++h) {
    mA[h] = *reinterpret_cast<const float4*>(mb + (size_t)h * DD + lane * 4);
    mB[h] = *reinterpret_cast<const float4*>(mb + (size_t)h * DD + 256 + lane * 4);
  }
  const float flg = flag[b];

  float acc[8] = {0.f, 0.f, 0.f, 0.f, 0.f, 0.f, 0.f, 0.f};

  for (int r = 0; r < RPW; ++r) {
    const int row = row0 + r;
    const float* xr = xin + (size_t)row * DD;
    float4 a0 = *reinterpret_cast<const float4*>(xr + lane * 4);
    float4 a1 = *reinterpret_cast<const float4*>(xr + 256 + lane * 4);
    float v[8] = {a0.x, a0.y, a0.z, a0.w, a1.x, a1.y, a1.z, a1.w};

    float s = 0.f, s2 = 0.f;
#pragma unroll
    for (int k = 0; k < 8; ++k) { s += v[k]; s2 += v[k] * v[k]; }
#pragma unroll
    for (int off = 32; off > 0; off >>= 1) {
      s  += __shfl_xor(s, off);
      s2 += __shfl_xor(s2, off);
    }
    const float mean = s * (1.f / (float)DD);
    const float var  = s2 * (1.f / (float)DD) - mean * mean;
    const float rstd = rsqrtf(var + EPS);

    float n[8];
#pragma unroll
    for (int k = 0; k < 8; ++k) n[k] = (v[k] - mean) * rstd * gv[k] + bv[k];

    float rel[HH];
#pragma unroll
    for (int h = 0; h < HH; ++h) {
      float p = n[0] * mA[h].x + n[1] * mA[h].y + n[2] * mA[h].z + n[3] * mA[h].w +
                n[4] * mB[h].x + n[5] * mB[h].y + n[6] * mB[h].z + n[7] * mB[h].w;
#pragma unroll
      for (int off = 32; off > 0; off >>= 1) p += __shfl_xor(p, off);
      rel[h] = p;
    }

    // gate MLP (all lanes redundantly; tiny, uniform scalar loads)
    float z = b2[0];
#pragma unroll
    for (int e = 0; e < 16; ++e) {
      float h1 = b1[e];
#pragma unroll
      for (int h = 0; h < HH; ++h) h1 += rel[h] * W1[e * HH + h];
      z += fmaxf(h1, 0.f) * W2[e];
    }
    const float sc = 1.f + flg * (1.f / (1.f + expf(-z)));

    float* orow = xout + (size_t)row * DD;
    *reinterpret_cast<float4*>(orow + lane * 4) =
        make_float4(v[0] * sc, v[1] * sc, v[2] * sc, v[3] * sc);
    *reinterpret_cast<float4*>(orow + 256 + lane * 4) =
        make_float4(v[4] * sc, v[5] * sc, v[6] * sc, v[7] * sc);

    // --- emit next phase's masked LN-sum contribution of y = v*sc ---
    if (emit && kpm_next[row] == 0) {   // wave-uniform
      const float mean_y = mean * sc;
      const float rstd_y = rsqrtf(var * sc * sc + EPS);
#pragma unroll
      for (int k = 0; k < 8; ++k)
        acc[k] += (v[k] * sc - mean_y) * rstd_y * gnv[k] + bnv[k];
    }
  }

  if (emit) {
#pragma unroll
    for (int k = 0; k < 4; ++k) {
      lds[wave][lane * 4 + k]       = acc[k];
      lds[wave][256 + lane * 4 + k] = acc[4 + k];
    }
    __syncthreads();
    const int tid = threadIdx.x;
    float s0 = lds[0][tid] + lds[1][tid] + lds[2][tid] + lds[3][tid];
    float s1 = lds[0][tid + 256] + lds[1][tid + 256] + lds[2][tid + 256] + lds[3][tid + 256];
    float* p = partial + ((size_t)b * NTILE + tile) * DD;
    p[tid]       = s0;
    p[tid + 256] = s1;
  }
}

// ---------------------------------------------------------------------------
extern "C" void kernel_launch(void* const* d_in, const int* in_sizes, int n_in,
                              void* d_out, int out_size, void* d_ws, size_t ws_size,
                              hipStream_t stream) {
  const float* x_vid = (const float*)d_in[0];
  const float* x_aud = (const float*)d_in[1];
  const int* vid_kpm = (const int*)d_in[2];
  const int* aud_kpm = (const int*)d_in[3];
  const float* Wq_vid         = (const float*)d_in[4];
  const float* Wk_aud_for_vid = (const float*)d_in[5];
  const float* Wq_aud         = (const float*)d_in[6];
  const float* Wk_vid_for_aud = (const float*)d_in[7];
  const float* vg_W1 = (const float*)d_in[8];
  const float* vg_b1 = (const float*)d_in[9];
  const float* vg_W2 = (const float*)d_in[10];
  const float* vg_b2 = (const float*)d_in[11];
  const float* ag_W1 = (const float*)d_in[12];
  const float* ag_b1 = (const float*)d_in[13];
  const float* ag_W2 = (const float*)d_in[14];
  const float* ag_b2 = (const float*)d_in[15];
  const float* vid_ln_g = (const float*)d_in[16];
  const float* vid_ln_b = (const float*)d_in[17];
  const float* aud_ln_g = (const float*)d_in[18];
  const float* aud_ln_b = (const float*)d_in[19];

  const size_t BTD = (size_t)BB * TT * DD;
  float* xv = (float*)d_out;        // working/output x_vid
  float* xa = xv + BTD;             // working/output x_aud

  float* partial = (float*)d_ws;                         // B*NTILE*D floats (1 MB)
  float* m       = partial + (size_t)BB * NTILE * DD;    // B*H*D
  float* flg     = m + (size_t)BB * HH * DD;             // B

  const size_t WW = (size_t)DD * DD;  // per-layer weight matrix stride

  // initial keys for phase A0: masked LN-sum of x_aud with vid_ln[0]
  ln_masked_sum_kernel<<<BB * NTILE, 256, 0, stream>>>(
      x_aud, aud_kpm, vid_ln_g, vid_ln_b, partial);

  for (int i = 0; i < NLAYER; ++i) {
    const float* srcV = (i == 0) ? x_vid : xv;
    const float* srcA = (i == 0) ? x_aud : xa;
    const int last = (i == NLAYER - 1);
    const size_t inext = last ? (size_t)i : (size_t)(i + 1);  // safe ptr when !emit

    // --- Phase A: vid gated by attn to aud (vid_ln both sides) ---
    prep_kernel<<<BB * HH, 256, 0, stream>>>(
        partial, aud_kpm, Wk_aud_for_vid + (size_t)i * WW, Wq_vid + (size_t)i * WW, m, flg);
    // update vid; emit partials for phase B keys: LN(xv_new, aud_ln[i]) masked by vid_kpm
    update_kernel<<<BB * NTILE, 256, 0, stream>>>(
        srcV, vid_ln_g + (size_t)i * DD, vid_ln_b + (size_t)i * DD, m, flg,
        vg_W1 + (size_t)i * 16 * HH, vg_b1 + (size_t)i * 16,
        vg_W2 + (size_t)i * 16, vg_b2 + i,
        vid_kpm, aud_ln_g + (size_t)i * DD, aud_ln_b + (size_t)i * DD,
        xv, partial, 1);

    // --- Phase B: aud gated by attn to UPDATED vid (aud_ln both sides) ---
    prep_kernel<<<BB * HH, 256, 0, stream>>>(
        partial, vid_kpm, Wk_vid_for_aud + (size_t)i * WW, Wq_aud + (size_t)i * WW, m, flg);
    // update aud; emit partials for next layer phase A keys: LN(xa_new, vid_ln[i+1]) masked by aud_kpm
    update_kernel<<<BB * NTILE, 256, 0, stream>>>(
        srcA, aud_ln_g + (size_t)i * DD, aud_ln_b + (size_t)i * DD, m, flg,
        ag_W1 + (size_t)i * 16 * HH, ag_b1 + (size_t)i * 16,
        ag_W2 + (size_t)i * 16, ag_b2 + i,
        aud_kpm, vid_ln_g + inext * DD, vid_ln_b + inext * DD,
        xa, partial, last ? 0 : 1);
  }
}

// Round 4
// 129.741 us; speedup vs baseline: 1.5763x; 1.5763x over previous
//
#include <hip/hip_runtime.h>
#include <math.h>

// Problem constants (B,T,D,H,L from the reference)
#define BB 4
#define TT 2048
#define DD 512
#define HH 8
#define NLAYER 2
#define EPS 1e-5f
#define SCALE 0.125f            // dh^-0.5, dh=64

#define NTILE 128               // partial tiles per batch (= emitter blocks/batch)
#define RPW 4                   // rows per wave in emitters (16 rows per block)

// ---------------------------------------------------------------------------
// Initial masked LN-sum (only for the very first phase's keys).
// Grid: BB*NTILE blocks, 256 threads; 4 waves x RPW rows; per-block LDS
// reduce -> partial[b][tile][d].
// ---------------------------------------------------------------------------
__global__ __launch_bounds__(256) void ln_masked_sum_kernel(
    const float* __restrict__ x,      // (B,T,D)
    const int*   __restrict__ kpm,    // (B,T) flat; nonzero = masked out
    const float* __restrict__ gamma,  // (D)
    const float* __restrict__ beta,   // (D)
    float* __restrict__ partial)      // (B, NTILE, D)
{
  const int bk   = blockIdx.x;
  const int wave = threadIdx.x >> 6;
  const int lane = threadIdx.x & 63;
  const int b    = bk >> 7;
  const int tile = bk & (NTILE - 1);
  const int row0 = bk * 16 + wave * RPW;   // global row = b*TT + t

  __shared__ float lds[4][DD];

  float4 g0 = *reinterpret_cast<const float4*>(gamma + lane * 4);
  float4 g1 = *reinterpret_cast<const float4*>(gamma + 256 + lane * 4);
  float4 be0 = *reinterpret_cast<const float4*>(beta + lane * 4);
  float4 be1 = *reinterpret_cast<const float4*>(beta + 256 + lane * 4);
  float gv[8] = {g0.x, g0.y, g0.z, g0.w, g1.x, g1.y, g1.z, g1.w};
  float bv[8] = {be0.x, be0.y, be0.z, be0.w, be1.x, be1.y, be1.z, be1.w};

  float acc[8] = {0.f, 0.f, 0.f, 0.f, 0.f, 0.f, 0.f, 0.f};

  for (int r = 0; r < RPW; ++r) {
    const int row = row0 + r;
    const float* xr = x + (size_t)row * DD;
    float4 a0 = *reinterpret_cast<const float4*>(xr + lane * 4);
    float4 a1 = *reinterpret_cast<const float4*>(xr + 256 + lane * 4);
    float v[8] = {a0.x, a0.y, a0.z, a0.w, a1.x, a1.y, a1.z, a1.w};
    float s = 0.f, s2 = 0.f;
#pragma unroll
    for (int k = 0; k < 8; ++k) { s += v[k]; s2 += v[k] * v[k]; }
#pragma unroll
    for (int off = 32; off > 0; off >>= 1) {
      s  += __shfl_xor(s, off);
      s2 += __shfl_xor(s2, off);
    }
    const float mean = s * (1.f / (float)DD);
    const float var  = s2 * (1.f / (float)DD) - mean * mean;
    const float rstd = rsqrtf(var + EPS);
    if (kpm[row] == 0) {   // wave-uniform branch
#pragma unroll
      for (int k = 0; k < 8; ++k) acc[k] += (v[k] - mean) * rstd * gv[k] + bv[k];
    }
  }

#pragma unroll
  for (int k = 0; k < 4; ++k) {
    lds[wave][lane * 4 + k]       = acc[k];
    lds[wave][256 + lane * 4 + k] = acc[4 + k];
  }
  __syncthreads();

  const int tid = threadIdx.x;
  float s0 = lds[0][tid] + lds[1][tid] + lds[2][tid] + lds[3][tid];
  float s1 = lds[0][tid + 256] + lds[1][tid + 256] + lds[2][tid + 256] + lds[3][tid + 256];
  float* p = partial + ((size_t)b * NTILE + tile) * DD;
  p[tid]       = s0;
  p[tid + 256] = s1;
}

// ---------------------------------------------------------------------------
// prep v2: per (b,h) block with 1024 threads (16 waves):
//   1. nsum[d] = sum of NTILE partial tiles (2-way tile split, 64 loads/thr)
//   2. valid count -> fac, flag
//   3. ks[j] = fac * Wk[h*64+j,:] . nsum   (4 coalesced row-dots per wave)
//   4. m[b,h,d] = sum_j Wq[h*64+j][d] * ks[j]  (2-way j split, 32 loads/thr)
// Grid: BB*HH = 32 blocks, 1024 threads.
// ---------------------------------------------------------------------------
__global__ __launch_bounds__(1024) void prep_kernel(
    const float* __restrict__ partial,  // (B,NTILE,D)
    const int*   __restrict__ kpm,      // (B,T) flat
    const float* __restrict__ Wk,       // (D,D) layer slice, row o, col d
    const float* __restrict__ Wq,       // (D,D) layer slice
    float* __restrict__ m,              // (B,H,D)
    float* __restrict__ flag)           // (B)
{
  const int b    = blockIdx.x >> 3;
  const int h    = blockIdx.x & 7;
  const int tid  = threadIdx.x;          // 0..1023
  const int wave = tid >> 6;             // 0..15
  const int lane = tid & 63;
  const int d    = tid & 511;
  const int half = tid >> 9;             // 0/1

  __shared__ float ns2[2][DD];   // 4 KB scratch (reused in step 4)
  __shared__ float nsum_s[DD];   // 2 KB
  __shared__ float ksl[64];
  __shared__ float csh[16];

  // 1. per-half tile reduce (64 coalesced-per-tile loads, 8-deep ILP)
  {
    const float* p = partial + ((size_t)b * NTILE + (size_t)half * 64) * DD + d;
    float s = 0.f;
#pragma unroll 8
    for (int w = 0; w < 64; ++w) s += p[(size_t)w * DD];
    ns2[half][d] = s;
  }

  // 2. valid count (1024 threads x 2 mask entries)
  {
    int cnt = (kpm[b * TT + tid] == 0) + (kpm[b * TT + 1024 + tid] == 0);
#pragma unroll
    for (int off = 32; off > 0; off >>= 1) cnt += __shfl_xor(cnt, off);
    if (lane == 0) csh[wave] = (float)cnt;
  }
  __syncthreads();

  if (tid < DD) nsum_s[tid] = ns2[0][tid] + ns2[1][tid];
  __syncthreads();

  float vc = 0.f;
#pragma unroll
  for (int k = 0; k < 16; ++k) vc += csh[k];
  if (h == 0 && tid == 0) flag[b] = (vc > 0.f) ? 1.f : 0.f;
  const float facv = SCALE / fmaxf(vc, 1.f);

  // 3. ks: 4 rows per wave, coalesced 2KB row loads + shuffle reduce
  float nl[8];
#pragma unroll
  for (int k = 0; k < 8; ++k) nl[k] = nsum_s[lane * 8 + k];
#pragma unroll
  for (int jj = 0; jj < 4; ++jj) {
    const int j = wave * 4 + jj;
    const float* wr = Wk + (size_t)(h * 64 + j) * DD + lane * 8;
    float4 w0 = *reinterpret_cast<const float4*>(wr);
    float4 w1 = *reinterpret_cast<const float4*>(wr + 4);
    float s = w0.x * nl[0] + w0.y * nl[1] + w0.z * nl[2] + w0.w * nl[3] +
              w1.x * nl[4] + w1.y * nl[5] + w1.z * nl[6] + w1.w * nl[7];
#pragma unroll
    for (int off = 32; off > 0; off >>= 1) s += __shfl_xor(s, off);
    if (lane == 0) ksl[j] = s * facv;
  }
  __syncthreads();

  // 4. m-slice: thread (d, jhalf) sums 32 j's (coalesced across d)
  {
    float s = 0.f;
    const float* base = Wq + (size_t)(h * 64 + half * 32) * DD + d;
#pragma unroll 8
    for (int j = 0; j < 32; ++j) s += base[(size_t)j * DD] * ksl[half * 32 + j];
    __syncthreads();            // ns2 free for reuse
    ns2[half][d] = s;
  }
  __syncthreads();
  if (tid < DD) m[((size_t)b * HH + h) * DD + tid] = ns2[0][tid] + ns2[1][tid];
}

// ---------------------------------------------------------------------------
// update: per-row LN, rel[h] = n . m[b,h,:], gate MLP, out = x*(1+flag*sig(z)).
// ALSO emits the NEXT phase's masked LN-sum partials from the freshly written
// output rows (LN stats of y = v*sc derived from v's stats for free).
// Grid: BB*NTILE = 512 blocks, 256 threads, 4 waves x RPW rows.
// ---------------------------------------------------------------------------
__global__ __launch_bounds__(256) void update_kernel(
    const float* __restrict__ xin,     // (B,T,D)
    const float* __restrict__ gamma,   // (D)   this phase's LN (query side)
    const float* __restrict__ beta,    // (D)
    const float* __restrict__ m,       // (B,H,D)
    const float* __restrict__ flag,    // (B)
    const float* __restrict__ W1,      // (16,8)
    const float* __restrict__ b1,      // (16)
    const float* __restrict__ W2,      // (16)
    const float* __restrict__ b2,      // (1)
    const int*   __restrict__ kpm_next,// (B,T) flat — next phase's KEY mask
    const float* __restrict__ gnext,   // (D)   next phase's LN gamma
    const float* __restrict__ bnext,   // (D)
    float* __restrict__ xout,          // (B,T,D)
    float* __restrict__ partial,       // (B,NTILE,D)
    int emit)
{
  const int bk   = blockIdx.x;
  const int wave = threadIdx.x >> 6;
  const int lane = threadIdx.x & 63;
  const int b    = bk >> 7;
  const int tile = bk & (NTILE - 1);
  const int row0 = bk * 16 + wave * RPW;

  __shared__ float lds[4][DD];

  float4 g0 = *reinterpret_cast<const float4*>(gamma + lane * 4);
  float4 g1 = *reinterpret_cast<const float4*>(gamma + 256 + lane * 4);
  float4 be0 = *reinterpret_cast<const float4*>(beta + lane * 4);
  float4 be1 = *reinterpret_cast<const float4*>(beta + 256 + lane * 4);
  float gv[8] = {g0.x, g0.y, g0.z, g0.w, g1.x, g1.y, g1.z, g1.w};
  float bv[8] = {be0.x, be0.y, be0.z, be0.w, be1.x, be1.y, be1.z, be1.w};

  float4 gn0 = *reinterpret_cast<const float4*>(gnext + lane * 4);
  float4 gn1 = *reinterpret_cast<const float4*>(gnext + 256 + lane * 4);
  float4 bn0 = *reinterpret_cast<const float4*>(bnext + lane * 4);
  float4 bn1 = *reinterpret_cast<const float4*>(bnext + 256 + lane * 4);
  float gnv[8] = {gn0.x, gn0.y, gn0.z, gn0.w, gn1.x, gn1.y, gn1.z, gn1.w};
  float bnv[8] = {bn0.x, bn0.y, bn0.z, bn0.w, bn1.x, bn1.y, bn1.z, bn1.w};

  const float* mb = m + (size_t)b * HH * DD;
  const float flg = flag[b];

  float acc[8] = {0.f, 0.f, 0.f, 0.f, 0.f, 0.f, 0.f, 0.f};

  for (int r = 0; r < RPW; ++r) {
    const int row = row0 + r;
    const float* xr = xin + (size_t)row * DD;
    float4 a0 = *reinterpret_cast<const float4*>(xr + lane * 4);
    float4 a1 = *reinterpret_cast<const float4*>(xr + 256 + lane * 4);
    float v[8] = {a0.x, a0.y, a0.z, a0.w, a1.x, a1.y, a1.z, a1.w};

    float s = 0.f, s2 = 0.f;
#pragma unroll
    for (int k = 0; k < 8; ++k) { s += v[k]; s2 += v[k] * v[k]; }
#pragma unroll
    for (int off = 32; off > 0; off >>= 1) {
      s  += __shfl_xor(s, off);
      s2 += __shfl_xor(s2, off);
    }
    const float mean = s * (1.f / (float)DD);
    const float var  = s2 * (1.f / (float)DD) - mean * mean;
    const float rstd = rsqrtf(var + EPS);

    float n[8];
#pragma unroll
    for (int k = 0; k < 8; ++k) n[k] = (v[k] - mean) * rstd * gv[k] + bv[k];

    float rel[HH];
#pragma unroll
    for (int h = 0; h < HH; ++h) {
      const float* mh = mb + (size_t)h * DD;
      float4 m0 = *reinterpret_cast<const float4*>(mh + lane * 4);
      float4 m1 = *reinterpret_cast<const float4*>(mh + 256 + lane * 4);
      float p = n[0] * m0.x + n[1] * m0.y + n[2] * m0.z + n[3] * m0.w +
                n[4] * m1.x + n[5] * m1.y + n[6] * m1.z + n[7] * m1.w;
#pragma unroll
      for (int off = 32; off > 0; off >>= 1) p += __shfl_xor(p, off);
      rel[h] = p;
    }

    // gate MLP (all lanes redundantly; tiny, uniform scalar loads)
    float z = b2[0];
#pragma unroll
    for (int e = 0; e < 16; ++e) {
      float h1 = b1[e];
#pragma unroll
      for (int h = 0; h < HH; ++h) h1 += rel[h] * W1[e * HH + h];
      z += fmaxf(h1, 0.f) * W2[e];
    }
    const float sc = 1.f + flg * (1.f / (1.f + expf(-z)));

    float* orow = xout + (size_t)row * DD;
    *reinterpret_cast<float4*>(orow + lane * 4) =
        make_float4(v[0] * sc, v[1] * sc, v[2] * sc, v[3] * sc);
    *reinterpret_cast<float4*>(orow + 256 + lane * 4) =
        make_float4(v[4] * sc, v[5] * sc, v[6] * sc, v[7] * sc);

    // --- emit next phase's masked LN-sum contribution of y = v*sc ---
    if (emit && kpm_next[row] == 0) {   // wave-uniform
      const float mean_y = mean * sc;
      const float rstd_y = rsqrtf(var * sc * sc + EPS);
#pragma unroll
      for (int k = 0; k < 8; ++k)
        acc[k] += (v[k] * sc - mean_y) * rstd_y * gnv[k] + bnv[k];
    }
  }

  if (emit) {
#pragma unroll
    for (int k = 0; k < 4; ++k) {
      lds[wave][lane * 4 + k]       = acc[k];
      lds[wave][256 + lane * 4 + k] = acc[4 + k];
    }
    __syncthreads();
    const int tid = threadIdx.x;
    float s0 = lds[0][tid] + lds[1][tid] + lds[2][tid] + lds[3][tid];
    float s1 = lds[0][tid + 256] + lds[1][tid + 256] + lds[2][tid + 256] + lds[3][tid + 256];
    float* p = partial + ((size_t)b * NTILE + tile) * DD;
    p[tid]       = s0;
    p[tid + 256] = s1;
  }
}

// ---------------------------------------------------------------------------
extern "C" void kernel_launch(void* const* d_in, const int* in_sizes, int n_in,
                              void* d_out, int out_size, void* d_ws, size_t ws_size,
                              hipStream_t stream) {
  const float* x_vid = (const float*)d_in[0];
  const float* x_aud = (const float*)d_in[1];
  const int* vid_kpm = (const int*)d_in[2];
  const int* aud_kpm = (const int*)d_in[3];
  const float* Wq_vid         = (const float*)d_in[4];
  const float* Wk_aud_for_vid = (const float*)d_in[5];
  const float* Wq_aud         = (const float*)d_in[6];
  const float* Wk_vid_for_aud = (const float*)d_in[7];
  const float* vg_W1 = (const float*)d_in[8];
  const float* vg_b1 = (const float*)d_in[9];
  const float* vg_W2 = (const float*)d_in[10];
  const float* vg_b2 = (const float*)d_in[11];
  const float* ag_W1 = (const float*)d_in[12];
  const float* ag_b1 = (const float*)d_in[13];
  const float* ag_W2 = (const float*)d_in[14];
  const float* ag_b2 = (const float*)d_in[15];
  const float* vid_ln_g = (const float*)d_in[16];
  const float* vid_ln_b = (const float*)d_in[17];
  const float* aud_ln_g = (const float*)d_in[18];
  const float* aud_ln_b = (const float*)d_in[19];

  const size_t BTD = (size_t)BB * TT * DD;
  float* xv = (float*)d_out;        // working/output x_vid
  float* xa = xv + BTD;             // working/output x_aud

  float* partial = (float*)d_ws;                         // B*NTILE*D floats (1 MB)
  float* m       = partial + (size_t)BB * NTILE * DD;    // B*H*D
  float* flg     = m + (size_t)BB * HH * DD;             // B

  const size_t WW = (size_t)DD * DD;  // per-layer weight matrix stride

  // initial keys for phase A0: masked LN-sum of x_aud with vid_ln[0]
  ln_masked_sum_kernel<<<BB * NTILE, 256, 0, stream>>>(
      x_aud, aud_kpm, vid_ln_g, vid_ln_b, partial);

  for (int i = 0; i < NLAYER; ++i) {
    const float* srcV = (i == 0) ? x_vid : xv;
    const float* srcA = (i == 0) ? x_aud : xa;
    const int last = (i == NLAYER - 1);
    const size_t inext = last ? (size_t)i : (size_t)(i + 1);  // safe ptr when !emit

    // --- Phase A: vid gated by attn to aud (vid_ln both sides) ---
    prep_kernel<<<BB * HH, 1024, 0, stream>>>(
        partial, aud_kpm, Wk_aud_for_vid + (size_t)i * WW, Wq_vid + (size_t)i * WW, m, flg);
    // update vid; emit partials for phase B keys: LN(xv_new, aud_ln[i]) masked by vid_kpm
    update_kernel<<<BB * NTILE, 256, 0, stream>>>(
        srcV, vid_ln_g + (size_t)i * DD, vid_ln_b + (size_t)i * DD, m, flg,
        vg_W1 + (size_t)i * 16 * HH, vg_b1 + (size_t)i * 16,
        vg_W2 + (size_t)i * 16, vg_b2 + i,
        vid_kpm, aud_ln_g + (size_t)i * DD, aud_ln_b + (size_t)i * DD,
        xv, partial, 1);

    // --- Phase B: aud gated by attn to UPDATED vid (aud_ln both sides) ---
    prep_kernel<<<BB * HH, 1024, 0, stream>>>(
        partial, vid_kpm, Wk_vid_for_aud + (size_t)i * WW, Wq_aud + (size_t)i * WW, m, flg);
    // update aud; emit partials for next layer phase A keys: LN(xa_new, vid_ln[i+1]) masked by aud_kpm
    update_kernel<<<BB * NTILE, 256, 0, stream>>>(
        srcA, aud_ln_g + (size_t)i * DD, aud_ln_b + (size_t)i * DD, m, flg,
        ag_W1 + (size_t)i * 16 * HH, ag_b1 + (size_t)i * 16,
        ag_W2 + (size_t)i * 16, ag_b2 + i,
        aud_kpm, vid_ln_g + inext * DD, vid_ln_b + inext * DD,
        xa, partial, last ? 0 : 1);
  }
}